// Round 7
// baseline (486.459 us; speedup 1.0000x reference)
//
#include <hip/hip_runtime.h>
#include <hip/hip_cooperative_groups.h>
#include <hip/hip_bf16.h>
#include <math.h>

namespace cg = cooperative_groups;

// Problem constants: H=8, d_model=256, N=128, d_k=32, B=32, rows=4096

typedef short short8 __attribute__((ext_vector_type(8)));
typedef float f32x4 __attribute__((ext_vector_type(4)));

union V8 { uint4 u; short8 s; };

struct Params {
    const float *x, *gumbel_u, *memory_w, *fc_out_w, *fc_out_b, *fc_cat_w, *fc_cat_b;
    const float *wq, *bq, *wk, *bk, *wv, *bv, *out_w, *out_b;
    const float *mlp_w1, *mlp_b1, *mlp_w2, *mlp_b2;
    float *A, *Bm, *hbuf, *xm, *q, *k, *v, *ao, *out;
    ushort *mask, *wf_hi, *wf_lo;
};

union SMem {
    struct { ushort xhi[16 * 264]; ushort xlo[16 * 264]; } g;   // 16896 B
    struct { float xs[32 * 132]; } w;                           // 16896 B
    struct { float sA[16 * 260]; float sB[16 * 260]; } c;       // 33280 B
    struct { ushort vT[32 * 136]; ushort ps[64 * 136]; } a;     // 26112 B
};

__device__ __forceinline__ float gelu_f(float x) {
    float inner = 0.7978845608028654f * (x + 0.044715f * x * x * x);
    return 0.5f * x * (1.0f + tanhf(inner));
}
__device__ __forceinline__ void split_bf16(float x, ushort& h, ushort& l) {
    __hip_bfloat16 bh = __float2bfloat16(x);          // RN
    float hf = __bfloat162float(bh);
    __hip_bfloat16 bl = __float2bfloat16(x - hf);
    h = __builtin_bit_cast(ushort, bh);
    l = __builtin_bit_cast(ushort, bl);
}
__device__ __forceinline__ ushort bf16bits(float x) {
    return __builtin_bit_cast(ushort, __float2bfloat16(x));
}
__device__ __forceinline__ float bits_to_f(ushort v) {
    return __builtin_bit_cast(float, ((uint)v) << 16);
}
__device__ __forceinline__ uint pk(float a, float b) {
    return (uint)bf16bits(a) | ((uint)bf16bits(b) << 16);
}
__device__ __forceinline__ short8 lds_frag(const ushort* p) {
    V8 v; v.u = *(const uint4*)p; return v.s;
}

// ---------------------------------------------------------------------------
// Phase 0: weight prep. 128 jobs = mat(8) x ks(8) x nhalf(2).
// Frag layout: elem (k,n) -> m*65536 + ((tg*8+ks)*64 + lane)*8 + j
// ---------------------------------------------------------------------------
__device__ void ph_wprep(const Params& P, SMem& sm, int bi, int t) {
    if (bi >= 128) return;
    int m = bi >> 4, ks = (bi >> 1) & 7, nh = bi & 1;
    const float* Wm[8] = { P.mlp_w1, P.mlp_w2, P.wq, P.wk, P.wv, P.out_w,
                           P.fc_out_w, P.fc_out_w + 65536 };
    const float* W = Wm[m];
    ushort* Hm = P.wf_hi + m * 65536;
    ushort* Lm = P.wf_lo + m * 65536;
    #pragma unroll
    for (int p = 0; p < 4; ++p) {
        int idx = p * 256 + t;
        int row = idx >> 5, c4 = (idx & 31) * 4;
        *(float4*)(sm.w.xs + row * 132 + c4) =
            *(const float4*)(W + (ks * 32 + row) * 256 + nh * 128 + c4);
    }
    __syncthreads();
    int lane = t & 63, lr = lane & 15, quad = lane >> 4;
    #pragma unroll
    for (int it = 0; it < 2; ++it) {
        int tgl = (t >> 6) + 4 * it;
        int tg = nh * 8 + tgl;
        int nl = tgl * 16 + lr;
        ushort hb[8], lb[8];
        #pragma unroll
        for (int j = 0; j < 8; ++j)
            split_bf16(sm.w.xs[(quad * 8 + j) * 132 + nl], hb[j], lb[j]);
        uint4 ph = { (uint)hb[0] | ((uint)hb[1] << 16), (uint)hb[2] | ((uint)hb[3] << 16),
                     (uint)hb[4] | ((uint)hb[5] << 16), (uint)hb[6] | ((uint)hb[7] << 16) };
        uint4 pl = { (uint)lb[0] | ((uint)lb[1] << 16), (uint)lb[2] | ((uint)lb[3] << 16),
                     (uint)lb[4] | ((uint)lb[5] << 16), (uint)lb[6] | ((uint)lb[7] << 16) };
        int idx = ((tg * 8 + ks) * 64 + lane) * 8;
        *(uint4*)(Hm + idx) = ph;
        *(uint4*)(Lm + idx) = pl;
    }
}

// ---------------------------------------------------------------------------
// Generic X-tile staging (fp32 row-major [.,256] -> bf16 hi/lo LDS frags)
// ---------------------------------------------------------------------------
__device__ void stage_x(SMem& sm, const float* X, int r0, int t) {
    __syncthreads();
    #pragma unroll
    for (int ii = 0; ii < 4; ++ii) {
        int f4 = ii * 256 + t;
        int row = f4 >> 6, c = (f4 & 63) * 4;
        float4 xv = *(const float4*)(X + (r0 + row) * 256 + c);
        ushort h[4], l[4];
        split_bf16(xv.x, h[0], l[0]); split_bf16(xv.y, h[1], l[1]);
        split_bf16(xv.z, h[2], l[2]); split_bf16(xv.w, h[3], l[3]);
        uint2 ph = { (uint)h[0] | ((uint)h[1] << 16), (uint)h[2] | ((uint)h[3] << 16) };
        uint2 pl = { (uint)l[0] | ((uint)l[1] << 16), (uint)l[2] | ((uint)l[3] << 16) };
        *(uint2*)(sm.g.xhi + row * 264 + c) = ph;
        *(uint2*)(sm.g.xlo + row * 264 + c) = pl;
    }
    __syncthreads();
}

// One wave computes one 16x16 output tile (coltile tg) over K=256, hi/lo.
__device__ f32x4 gemm_wave(const SMem& sm, const ushort* Whi, const ushort* Wlo,
                           int tg, int lane) {
    int lr = lane & 15, quad = lane >> 4;
    const ushort* ah = sm.g.xhi + lr * 264 + quad * 8;
    const ushort* al = sm.g.xlo + lr * 264 + quad * 8;
    const uint4* H4 = (const uint4*)Whi;
    const uint4* L4 = (const uint4*)Wlo;
    f32x4 acc = {};
    #pragma unroll 4
    for (int ks = 0; ks < 8; ++ks) {
        short8 a_h = lds_frag(ah + ks * 32);
        short8 a_l = lds_frag(al + ks * 32);
        int off = (tg * 8 + ks) * 64 + lane;
        V8 bh, bl; bh.u = H4[off]; bl.u = L4[off];
        acc = __builtin_amdgcn_mfma_f32_16x16x32_bf16(a_h, bh.s, acc, 0, 0, 0);
        acc = __builtin_amdgcn_mfma_f32_16x16x32_bf16(a_l, bh.s, acc, 0, 0, 0);
        acc = __builtin_amdgcn_mfma_f32_16x16x32_bf16(a_h, bl.s, acc, 0, 0, 0);
    }
    return acc;
}

// ---------------------------------------------------------------------------
// Phase 1a: featproj. 512 jobs: rt=bi&63, y=bi>>6 -> msel=y&1, cq=y>>1.
// ---------------------------------------------------------------------------
__device__ void ph_featproj(const Params& P, SMem& sm, int bi, int t) {
    int rt = bi & 63;
    int y = bi >> 6;
    int msel = y & 1, cq = y >> 1;
    __syncthreads();
    #pragma unroll
    for (int ii = 0; ii < 4; ++ii) {
        int f4 = ii * 256 + t;
        int rr = f4 >> 6, c = (f4 & 63) * 4;
        int r = rt * 16 + rr;
        int h = r >> 7, n = r & 127;
        float4 xv = *(const float4*)(P.memory_w + n * 2048 + h * 256 + c);
        ushort hh[4], ll[4];
        split_bf16(xv.x, hh[0], ll[0]); split_bf16(xv.y, hh[1], ll[1]);
        split_bf16(xv.z, hh[2], ll[2]); split_bf16(xv.w, hh[3], ll[3]);
        uint2 ph = { (uint)hh[0] | ((uint)hh[1] << 16), (uint)hh[2] | ((uint)hh[3] << 16) };
        uint2 pl = { (uint)ll[0] | ((uint)ll[1] << 16), (uint)ll[2] | ((uint)ll[3] << 16) };
        *(uint2*)(sm.g.xhi + rr * 264 + c) = ph;
        *(uint2*)(sm.g.xlo + rr * 264 + c) = pl;
    }
    __syncthreads();
    int lane = t & 63, w = t >> 6;
    int lr = lane & 15, quad = lane >> 4;
    int tg = cq * 4 + w;
    f32x4 acc = gemm_wave(sm, P.wf_hi + (6 + msel) * 65536,
                          P.wf_lo + (6 + msel) * 65536, tg, lane);
    float* O = msel ? P.Bm : P.A;
    int n0 = tg * 16 + lr;
    #pragma unroll
    for (int r = 0; r < 4; ++r)
        O[(rt * 16 + quad * 4 + r) * 256 + n0] = acc[r];
}

// ---------------------------------------------------------------------------
// Phase 1b: mlp1 (gelu). rt=bi&255, h2=bi>>8 -> cq = h2*2 + {0,1}.
// ---------------------------------------------------------------------------
__device__ void ph_mlp1(const Params& P, SMem& sm, int bi, int t) {
    int rt = bi & 255, h2 = bi >> 8;
    stage_x(sm, P.x, rt * 16, t);
    int lane = t & 63, w = t >> 6;
    int lr = lane & 15, quad = lane >> 4;
    #pragma unroll
    for (int i = 0; i < 2; ++i) {
        int tg = (h2 * 2 + i) * 4 + w;
        f32x4 acc = gemm_wave(sm, P.wf_hi, P.wf_lo, tg, lane);
        int n0 = tg * 16 + lr;
        float bs = P.mlp_b1[n0];
        #pragma unroll
        for (int r = 0; r < 4; ++r)
            P.hbuf[(rt * 16 + quad * 4 + r) * 256 + n0] = gelu_f(acc[r] + bs);
    }
}

// ---------------------------------------------------------------------------
// Phase 2a: conn. 512 jobs: h=bi>>6, it=(bi>>3)&7, jt=bi&7.
// ---------------------------------------------------------------------------
__device__ void ph_conn(const Params& P, SMem& sm, int bi, int t) {
    int h = bi >> 6, it = (bi >> 3) & 7, jt = bi & 7;
    int i0 = it * 16, j0 = jt * 16;
    int il = t >> 4, jl = t & 15;
    __syncthreads();
    #pragma unroll
    for (int p = 0; p < 4; ++p) {
        int idx = p * 256 + t;
        int rr = idx >> 6, c = (idx & 63) * 4;
        *(float4*)(sm.c.sA + rr * 260 + c) =
            *(const float4*)(P.A + (h * 128 + j0 + rr) * 256 + c);
        float4 bv = *(const float4*)(P.Bm + (h * 128 + i0 + rr) * 256 + c);
        float4 fb = *(const float4*)(P.fc_out_b + c);
        bv.x += fb.x; bv.y += fb.y; bv.z += fb.z; bv.w += fb.w;
        *(float4*)(sm.c.sB + rr * 260 + c) = bv;
    }
    __syncthreads();
    const float* Ar = sm.c.sA + jl * 260;
    const float* Br = sm.c.sB + il * 260;
    float l0 = P.fc_cat_b[0], l1 = P.fc_cat_b[1];
    #pragma unroll 4
    for (int d4 = 0; d4 < 64; ++d4) {
        int d = d4 * 4;
        float4 av = *(const float4*)(Ar + d);
        float4 bv = *(const float4*)(Br + d);
        float4 cwA = *(const float4*)(P.fc_cat_w + d * 2);
        float4 cwB = *(const float4*)(P.fc_cat_w + d * 2 + 4);
        float h0 = fmaxf(av.x + bv.x, 0.f);
        float h1 = fmaxf(av.y + bv.y, 0.f);
        float h2 = fmaxf(av.z + bv.z, 0.f);
        float h3 = fmaxf(av.w + bv.w, 0.f);
        l0 += h0 * cwA.x + h1 * cwA.z + h2 * cwB.x + h3 * cwB.z;
        l1 += h0 * cwA.y + h1 * cwA.w + h2 * cwB.y + h3 * cwB.w;
    }
    int i = i0 + il, j = j0 + jl;
    float2 uu = *(const float2*)(P.gumbel_u + ((h * 128 + i) * 128 + j) * 2);
    float g0 = -logf(-logf(uu.x + 1e-10f) + 1e-10f);
    float g1 = -logf(-logf(uu.y + 1e-10f) + 1e-10f);
    bool on = (l1 + g1) > (l0 + g0);
    P.mask[(h * 128 + i) * 128 + j] = bf16bits(on ? 0.f : -1e9f);
}

// ---------------------------------------------------------------------------
// Phase 2b: mlp2 (no act). Same mapping as mlp1.
// ---------------------------------------------------------------------------
__device__ void ph_mlp2(const Params& P, SMem& sm, int bi, int t) {
    int rt = bi & 255, h2 = bi >> 8;
    stage_x(sm, P.hbuf, rt * 16, t);
    int lane = t & 63, w = t >> 6;
    int lr = lane & 15, quad = lane >> 4;
    #pragma unroll
    for (int i = 0; i < 2; ++i) {
        int tg = (h2 * 2 + i) * 4 + w;
        f32x4 acc = gemm_wave(sm, P.wf_hi + 65536, P.wf_lo + 65536, tg, lane);
        int n0 = tg * 16 + lr;
        float bs = P.mlp_b2[n0];
        #pragma unroll
        for (int r = 0; r < 4; ++r)
            P.xm[(rt * 16 + quad * 4 + r) * 256 + n0] = acc[r] + bs;
    }
}

// ---------------------------------------------------------------------------
// Phase 3: qkv. rt=bi&255, h2=bi>>8 -> 6 combos c = h2*6+j; osel=c>>2, cq=c&3.
// One staged X tile serves all 6 combos.
// ---------------------------------------------------------------------------
__device__ void ph_qkv(const Params& P, SMem& sm, int bi, int t) {
    int rt = bi & 255, h2 = bi >> 8;
    stage_x(sm, P.xm, rt * 16, t);
    int lane = t & 63, w = t >> 6;
    int lr = lane & 15, quad = lane >> 4;
    #pragma unroll
    for (int j = 0; j < 6; ++j) {
        int c = h2 * 6 + j;
        int osel = c >> 2, cq = c & 3;
        int tg = cq * 4 + w;
        f32x4 acc = gemm_wave(sm, P.wf_hi + (2 + osel) * 65536,
                              P.wf_lo + (2 + osel) * 65536, tg, lane);
        const float* Bp = osel == 0 ? P.bq : osel == 1 ? P.bk : P.bv;
        float* O = osel == 0 ? P.q : osel == 1 ? P.k : P.v;
        int n0 = tg * 16 + lr;
        float bs = Bp[n0];
        #pragma unroll
        for (int r = 0; r < 4; ++r)
            O[(rt * 16 + quad * 4 + r) * 256 + n0] = acc[r] + bs;
    }
}

// ---------------------------------------------------------------------------
// Phase 4: attention. 512 jobs: b=bi>>4, h=(bi>>1)&7, rh=bi&1.
// 4 waves; wave w -> row tile rt = rh*4 + w (16 q-rows).
// ---------------------------------------------------------------------------
__device__ void ph_attn(const Params& P, SMem& sm, int bi, int t) {
    int b = bi >> 4, h = (bi >> 1) & 7, rh = bi & 1;
    int lane = t & 63, w = t >> 6;
    __syncthreads();
    #pragma unroll
    for (int it = 0; it < 4; ++it) {
        int f4 = it * 256 + t;
        int key = f4 >> 3, dq = (f4 & 7) * 4;
        float4 vv = *(const float4*)(P.v + b * 32768 + key * 256 + h * 32 + dq);
        sm.a.vT[(dq + 0) * 136 + key] = bf16bits(vv.x);
        sm.a.vT[(dq + 1) * 136 + key] = bf16bits(vv.y);
        sm.a.vT[(dq + 2) * 136 + key] = bf16bits(vv.z);
        sm.a.vT[(dq + 3) * 136 + key] = bf16bits(vv.w);
    }
    __syncthreads();
    int lr = lane & 15, quad = lane >> 4;
    int rt = rh * 4 + w;
    const float* qp = P.q + b * 32768 + (rt * 16 + lr) * 256 + h * 32 + quad * 8;
    float4 q0 = *(const float4*)qp, q1 = *(const float4*)(qp + 4);
    V8 af;
    af.u.x = pk(q0.x, q0.y); af.u.y = pk(q0.z, q0.w);
    af.u.z = pk(q1.x, q1.y); af.u.w = pk(q1.z, q1.w);
    f32x4 s[8];
    #pragma unroll
    for (int ct = 0; ct < 8; ++ct) {
        const float* kp = P.k + b * 32768 + (ct * 16 + lr) * 256 + h * 32 + quad * 8;
        float4 k0 = *(const float4*)kp, k1 = *(const float4*)(kp + 4);
        V8 bf_;
        bf_.u.x = pk(k0.x, k0.y); bf_.u.y = pk(k0.z, k0.w);
        bf_.u.z = pk(k1.x, k1.y); bf_.u.w = pk(k1.z, k1.w);
        f32x4 z = {0.f, 0.f, 0.f, 0.f};
        s[ct] = __builtin_amdgcn_mfma_f32_16x16x32_bf16(af.s, bf_.s, z, 0, 0, 0);
    }
    const float scale = 0.17677669529663687f;  // 32^-0.5
    const ushort* mrow = P.mask + h * 16384;
    #pragma unroll
    for (int r = 0; r < 4; ++r) {
        int lrow = w * 16 + quad * 4 + r;
        int grow = rt * 16 + quad * 4 + r;
        float sv[8];
        float mx = -3.0e38f;
        #pragma unroll
        for (int ct = 0; ct < 8; ++ct) {
            float bias = bits_to_f(mrow[grow * 128 + ct * 16 + lr]);
            sv[ct] = s[ct][r] * scale + bias;
            mx = fmaxf(mx, sv[ct]);
        }
        mx = fmaxf(mx, __shfl_xor(mx, 1));
        mx = fmaxf(mx, __shfl_xor(mx, 2));
        mx = fmaxf(mx, __shfl_xor(mx, 4));
        mx = fmaxf(mx, __shfl_xor(mx, 8));
        float sum = 0.f;
        #pragma unroll
        for (int ct = 0; ct < 8; ++ct) {
            sv[ct] = __expf(sv[ct] - mx);
            sum += sv[ct];
        }
        sum += __shfl_xor(sum, 1);
        sum += __shfl_xor(sum, 2);
        sum += __shfl_xor(sum, 4);
        sum += __shfl_xor(sum, 8);
        float iv = 1.f / sum;
        #pragma unroll
        for (int ct = 0; ct < 8; ++ct)
            sm.a.ps[lrow * 136 + ct * 16 + lr] = bf16bits(sv[ct] * iv);
    }
    f32x4 o0 = {}, o1 = {};
    #pragma unroll
    for (int kk = 0; kk < 4; ++kk) {
        short8 pa = lds_frag(sm.a.ps + (w * 16 + lr) * 136 + kk * 32 + quad * 8);
        short8 v0 = lds_frag(sm.a.vT + lr * 136 + kk * 32 + quad * 8);
        short8 v1 = lds_frag(sm.a.vT + (16 + lr) * 136 + kk * 32 + quad * 8);
        o0 = __builtin_amdgcn_mfma_f32_16x16x32_bf16(pa, v0, o0, 0, 0, 0);
        o1 = __builtin_amdgcn_mfma_f32_16x16x32_bf16(pa, v1, o1, 0, 0, 0);
    }
    #pragma unroll
    for (int r = 0; r < 4; ++r) {
        int grow = rt * 16 + quad * 4 + r;
        float* op = P.ao + b * 32768 + grow * 256 + h * 32;
        op[lr] = o0[r];
        op[16 + lr] = o1[r];
    }
}

// ---------------------------------------------------------------------------
// Phase 5: output projection. Same mapping as mlp2, weights mat 5.
// ---------------------------------------------------------------------------
__device__ void ph_out(const Params& P, SMem& sm, int bi, int t) {
    int rt = bi & 255, h2 = bi >> 8;
    stage_x(sm, P.ao, rt * 16, t);
    int lane = t & 63, w = t >> 6;
    int lr = lane & 15, quad = lane >> 4;
    #pragma unroll
    for (int i = 0; i < 2; ++i) {
        int tg = (h2 * 2 + i) * 4 + w;
        f32x4 acc = gemm_wave(sm, P.wf_hi + 5 * 65536, P.wf_lo + 5 * 65536, tg, lane);
        int n0 = tg * 16 + lr;
        float bs = P.out_b[n0];
        #pragma unroll
        for (int r = 0; r < 4; ++r)
            P.out[(rt * 16 + quad * 4 + r) * 256 + n0] = acc[r] + bs;
    }
}

// ---------------------------------------------------------------------------
// Mega kernel (cooperative) — all phases with grid syncs.
// 512 blocks x 256 threads, 2 blocks/CU guaranteed co-resident.
// ---------------------------------------------------------------------------
__global__ __launch_bounds__(256, 2) void k_mega(Params P) {
    cg::grid_group grid = cg::this_grid();
    __shared__ SMem sm;
    int bi = blockIdx.x, t = threadIdx.x;
    ph_wprep(P, sm, bi, t);
    grid.sync();
    ph_featproj(P, sm, bi, t);
    ph_mlp1(P, sm, bi, t);
    grid.sync();
    ph_conn(P, sm, bi, t);
    ph_mlp2(P, sm, bi, t);
    grid.sync();
    ph_qkv(P, sm, bi, t);
    grid.sync();
    ph_attn(P, sm, bi, t);
    grid.sync();
    ph_out(P, sm, bi, t);
}

// Fallback: phases as separate plain launches (all grid 512 x 256).
template <int PH>
__global__ __launch_bounds__(256, 2) void k_phase(Params P) {
    __shared__ SMem sm;
    int bi = blockIdx.x, t = threadIdx.x;
    if (PH == 0) ph_wprep(P, sm, bi, t);
    if (PH == 1) { ph_featproj(P, sm, bi, t); ph_mlp1(P, sm, bi, t); }
    if (PH == 2) { ph_conn(P, sm, bi, t); ph_mlp2(P, sm, bi, t); }
    if (PH == 3) ph_qkv(P, sm, bi, t);
    if (PH == 4) ph_attn(P, sm, bi, t);
    if (PH == 5) ph_out(P, sm, bi, t);
}

// ---------------------------------------------------------------------------
extern "C" void kernel_launch(void* const* d_in, const int* in_sizes, int n_in,
                              void* d_out, int out_size, void* d_ws, size_t ws_size,
                              hipStream_t stream) {
    float* ws = (float*)d_ws;
    Params P;
    P.x        = (const float*)d_in[0];
    P.gumbel_u = (const float*)d_in[1];
    P.memory_w = (const float*)d_in[2];
    P.fc_out_w = (const float*)d_in[3];
    P.fc_out_b = (const float*)d_in[4];
    P.fc_cat_w = (const float*)d_in[5];
    P.fc_cat_b = (const float*)d_in[6];
    P.wq       = (const float*)d_in[7];
    P.bq       = (const float*)d_in[8];
    P.wk       = (const float*)d_in[9];
    P.bk       = (const float*)d_in[10];
    P.wv       = (const float*)d_in[11];
    P.bv       = (const float*)d_in[12];
    P.out_w    = (const float*)d_in[13];
    P.out_b    = (const float*)d_in[14];
    P.mlp_w1   = (const float*)d_in[15];
    P.mlp_b1   = (const float*)d_in[16];
    P.mlp_w2   = (const float*)d_in[17];
    P.mlp_b2   = (const float*)d_in[18];
    P.A     = ws;                   //  262144 f
    P.Bm    = ws + 262144;          //  262144 f
    P.mask  = (ushort*)(ws + 524288);    // 131072 ushort
    P.hbuf  = ws + 589824;          // 1048576 f
    P.xm    = ws + 1638400;         // 1048576 f
    P.q     = ws + 2686976;         // 1048576 f
    P.k     = ws + 3735552;         // 1048576 f
    P.v     = ws + 4784128;         // 1048576 f
    P.ao    = ws + 5832704;         // 1048576 f
    P.wf_hi = (ushort*)(ws + 6881280);   // 8*65536 ushort
    P.wf_lo = P.wf_hi + 8 * 65536;
    P.out   = (float*)d_out;

    void* args[] = { &P };
    hipError_t e = hipLaunchCooperativeKernel((const void*)k_mega, dim3(512),
                                              dim3(256), args, 0, stream);
    if (e != hipSuccess) {
        (void)hipGetLastError();  // clear error state; use plain-launch fallback
        k_phase<0><<<dim3(512), dim3(256), 0, stream>>>(P);
        k_phase<1><<<dim3(512), dim3(256), 0, stream>>>(P);
        k_phase<2><<<dim3(512), dim3(256), 0, stream>>>(P);
        k_phase<3><<<dim3(512), dim3(256), 0, stream>>>(P);
        k_phase<4><<<dim3(512), dim3(256), 0, stream>>>(P);
        k_phase<5><<<dim3(512), dim3(256), 0, stream>>>(P);
    }
}

// Round 9
// 159.219 us; speedup vs baseline: 3.0553x; 3.0553x over previous
//
#include <hip/hip_runtime.h>
#include <hip/hip_bf16.h>
#include <math.h>

// Problem constants: H=8, d_model=256, N=128, d_k=32, B=32, rows=4096

typedef short short8 __attribute__((ext_vector_type(8)));
typedef float f32x4 __attribute__((ext_vector_type(4)));

union V8 { uint4 u; short8 s; };

__device__ __forceinline__ float gelu_f(float x) {
    float inner = 0.7978845608028654f * (x + 0.044715f * x * x * x);
    return 0.5f * x * (1.0f + tanhf(inner));
}
__device__ __forceinline__ void split_bf16(float x, ushort& h, ushort& l) {
    __hip_bfloat16 bh = __float2bfloat16(x);          // RN
    float hf = __bfloat162float(bh);
    __hip_bfloat16 bl = __float2bfloat16(x - hf);
    h = __builtin_bit_cast(ushort, bh);
    l = __builtin_bit_cast(ushort, bl);
}
__device__ __forceinline__ ushort bf16bits(float x) {
    return __builtin_bit_cast(ushort, __float2bfloat16(x));
}
__device__ __forceinline__ float bits_to_f(ushort v) {
    return __builtin_bit_cast(float, ((uint)v) << 16);
}
__device__ __forceinline__ short8 lds_frag(const ushort* p) {
    V8 v; v.u = *(const uint4*)p; return v.s;
}

// ---------------------------------------------------------------------------
// Weight prep (coalesced): 8 mats of W[256k x 256n] fp32 -> frag-ordered bf16
// hi/lo. Frag: elem (k,n) -> m*65536 + ((tg*8+ks)*64 + lane)*8 + j,
// tg=n>>4, lr=n&15, ks=k>>5, quad=(k>>3)&3, j=k&7, lane=quad*16+lr.
// Mats: 0=mlp_w1 1=mlp_w2 2=wq 3=wk 4=wv 5=out_w 6=fc_out_w[0:256] 7=[256:512]
// grid 128 = mat(8) x ks(8) x nhalf(2); 256 threads.
// ---------------------------------------------------------------------------
__global__ __launch_bounds__(256) void k_wprep(
    const float* __restrict__ w0, const float* __restrict__ w1,
    const float* __restrict__ w2, const float* __restrict__ w3,
    const float* __restrict__ w4, const float* __restrict__ w5,
    const float* __restrict__ w6, const float* __restrict__ w7,
    ushort* __restrict__ hi, ushort* __restrict__ lo) {
    int bx = blockIdx.x;
    int m = bx >> 4, ks = (bx >> 1) & 7, nh = bx & 1;
    const float* W = m == 0 ? w0 : m == 1 ? w1 : m == 2 ? w2 : m == 3 ? w3 :
                     m == 4 ? w4 : m == 5 ? w5 : m == 6 ? w6 : w7;
    ushort* Hm = hi + m * 65536;
    ushort* Lm = lo + m * 65536;
    __shared__ __align__(16) float xs[32 * 132];
    int t = threadIdx.x;
    #pragma unroll
    for (int p = 0; p < 4; ++p) {
        int idx = p * 256 + t;
        int row = idx >> 5, c4 = (idx & 31) * 4;
        *(float4*)(xs + row * 132 + c4) =
            *(const float4*)(W + (ks * 32 + row) * 256 + nh * 128 + c4);
    }
    __syncthreads();
    int lane = t & 63, lr = lane & 15, quad = lane >> 4;
    #pragma unroll
    for (int it = 0; it < 2; ++it) {
        int tgl = (t >> 6) + 4 * it;
        int tg = nh * 8 + tgl;
        int nl = tgl * 16 + lr;
        ushort hb[8], lb[8];
        #pragma unroll
        for (int j = 0; j < 8; ++j)
            split_bf16(xs[(quad * 8 + j) * 132 + nl], hb[j], lb[j]);
        uint4 ph = { (uint)hb[0] | ((uint)hb[1] << 16), (uint)hb[2] | ((uint)hb[3] << 16),
                     (uint)hb[4] | ((uint)hb[5] << 16), (uint)hb[6] | ((uint)hb[7] << 16) };
        uint4 pl = { (uint)lb[0] | ((uint)lb[1] << 16), (uint)lb[2] | ((uint)lb[3] << 16),
                     (uint)lb[4] | ((uint)lb[5] << 16), (uint)lb[6] | ((uint)lb[7] << 16) };
        int idx = ((tg * 8 + ks) * 64 + lane) * 8;
        *(uint4*)(Hm + idx) = ph;
        *(uint4*)(Lm + idx) = pl;
    }
}

// ---------------------------------------------------------------------------
// featproj (MFMA): A/Bm[1024,256] = feats @ {W_top|W_bot}.
// feats row r=(h*128+n): memory_w[n*2048 + h*256 + :].
// grid (64 rowtiles, 8): y = colquad*2 + matsel; 256 thr, wave w -> tg=cq*4+w.
// ---------------------------------------------------------------------------
__global__ __launch_bounds__(256) void k_featproj(
    const float* __restrict__ memory_w,
    const ushort* __restrict__ Whi, const ushort* __restrict__ Wlo,
    float* __restrict__ A, float* __restrict__ Bm) {
    __shared__ __align__(16) ushort xhi[16 * 264], xlo[16 * 264];
    int t = threadIdx.x;
    int rt = blockIdx.x;
    int msel = blockIdx.y & 1, cq = blockIdx.y >> 1;
    #pragma unroll
    for (int ii = 0; ii < 4; ++ii) {
        int f4 = ii * 256 + t;
        int rr = f4 >> 6, c = (f4 & 63) * 4;
        int r = rt * 16 + rr;
        int h = r >> 7, n = r & 127;
        float4 xv = *(const float4*)(memory_w + n * 2048 + h * 256 + c);
        ushort hh[4], ll[4];
        split_bf16(xv.x, hh[0], ll[0]); split_bf16(xv.y, hh[1], ll[1]);
        split_bf16(xv.z, hh[2], ll[2]); split_bf16(xv.w, hh[3], ll[3]);
        uint2 ph = { (uint)hh[0] | ((uint)hh[1] << 16), (uint)hh[2] | ((uint)hh[3] << 16) };
        uint2 pl = { (uint)ll[0] | ((uint)ll[1] << 16), (uint)ll[2] | ((uint)ll[3] << 16) };
        *(uint2*)(xhi + rr * 264 + c) = ph;
        *(uint2*)(xlo + rr * 264 + c) = pl;
    }
    __syncthreads();
    int l = t & 63, w = t >> 6;
    int lr = l & 15, quad = l >> 4;
    int tg = cq * 4 + w;
    const uint4* H4 = (const uint4*)(Whi + (6 + msel) * 65536);
    const uint4* L4 = (const uint4*)(Wlo + (6 + msel) * 65536);
    const ushort* ah = xhi + lr * 264 + quad * 8;
    const ushort* al = xlo + lr * 264 + quad * 8;
    f32x4 acc = {};
    #pragma unroll
    for (int ks = 0; ks < 8; ++ks) {
        short8 a_h = lds_frag(ah + ks * 32);
        short8 a_l = lds_frag(al + ks * 32);
        int off = (tg * 8 + ks) * 64 + l;
        V8 bh, bl; bh.u = H4[off]; bl.u = L4[off];
        acc = __builtin_amdgcn_mfma_f32_16x16x32_bf16(a_h, bh.s, acc, 0, 0, 0);
        acc = __builtin_amdgcn_mfma_f32_16x16x32_bf16(a_l, bh.s, acc, 0, 0, 0);
        acc = __builtin_amdgcn_mfma_f32_16x16x32_bf16(a_h, bl.s, acc, 0, 0, 0);
    }
    float* O = msel ? Bm : A;
    int n0 = tg * 16 + lr;
    #pragma unroll
    for (int r = 0; r < 4; ++r)
        O[(rt * 16 + quad * 4 + r) * 256 + n0] = acc[r];
}

// ---------------------------------------------------------------------------
// conn (LDS-tiled): maskb[h,i,j] = bf16( conn ? 0 : -1e9 ).
// grid 512 = h(8) x itile(8) x jtile(8); 256 thr = (il) x (jl).
// ---------------------------------------------------------------------------
__global__ __launch_bounds__(256) void k_conn(
    const float* __restrict__ A, const float* __restrict__ Bm,
    const float* __restrict__ fc_out_b, const float* __restrict__ fc_cat_w,
    const float* __restrict__ fc_cat_b, const float* __restrict__ gumbel_u,
    ushort* __restrict__ maskb) {
    int bx = blockIdx.x;
    int h = bx >> 6, it = (bx >> 3) & 7, jt = bx & 7;
    int i0 = it * 16, j0 = jt * 16;
    int t = threadIdx.x;
    int il = t >> 4, jl = t & 15;
    __shared__ __align__(16) float sA[16 * 260], sB[16 * 260];
    #pragma unroll
    for (int p = 0; p < 4; ++p) {
        int idx = p * 256 + t;
        int rr = idx >> 6, c = (idx & 63) * 4;
        *(float4*)(sA + rr * 260 + c) =
            *(const float4*)(A + (h * 128 + j0 + rr) * 256 + c);
        float4 bv = *(const float4*)(Bm + (h * 128 + i0 + rr) * 256 + c);
        float4 fb = *(const float4*)(fc_out_b + c);
        bv.x += fb.x; bv.y += fb.y; bv.z += fb.z; bv.w += fb.w;
        *(float4*)(sB + rr * 260 + c) = bv;
    }
    __syncthreads();
    const float* Ar = sA + jl * 260;
    const float* Br = sB + il * 260;
    float l0 = fc_cat_b[0], l1 = fc_cat_b[1];
    #pragma unroll 4
    for (int d4 = 0; d4 < 64; ++d4) {
        int d = d4 * 4;
        float4 av = *(const float4*)(Ar + d);
        float4 bv = *(const float4*)(Br + d);
        float4 cwA = *(const float4*)(fc_cat_w + d * 2);
        float4 cwB = *(const float4*)(fc_cat_w + d * 2 + 4);
        float h0 = fmaxf(av.x + bv.x, 0.f);
        float h1 = fmaxf(av.y + bv.y, 0.f);
        float h2 = fmaxf(av.z + bv.z, 0.f);
        float h3 = fmaxf(av.w + bv.w, 0.f);
        l0 += h0 * cwA.x + h1 * cwA.z + h2 * cwB.x + h3 * cwB.z;
        l1 += h0 * cwA.y + h1 * cwA.w + h2 * cwB.y + h3 * cwB.w;
    }
    int i = i0 + il, j = j0 + jl;
    float2 uu = *(const float2*)(gumbel_u + ((h * 128 + i) * 128 + j) * 2);
    float g0 = -logf(-logf(uu.x + 1e-10f) + 1e-10f);
    float g1 = -logf(-logf(uu.y + 1e-10f) + 1e-10f);
    bool on = (l1 + g1) > (l0 + g0);
    maskb[(h * 128 + i) * 128 + j] = bf16bits(on ? 0.f : -1e9f);
}

// ---------------------------------------------------------------------------
// Fused mlp1(gelu) -> mlp2 -> qkv. 256 blocks x 16 rows, 512 thr = 8 waves.
// LDS hi/lo handoffs; Q/K/V written as bf16 (same rounding point the R6
// attention used via pk()). Wave w owns coltiles w*2, w*2+1 per stage.
// ---------------------------------------------------------------------------
__global__ __launch_bounds__(512) void k_fused3(
    const float* __restrict__ X,
    const ushort* __restrict__ Whi, const ushort* __restrict__ Wlo,
    const float* __restrict__ b1, const float* __restrict__ b2,
    const float* __restrict__ Bq, const float* __restrict__ Bk,
    const float* __restrict__ Bv,
    ushort* __restrict__ Q, ushort* __restrict__ K, ushort* __restrict__ V) {
    __shared__ __align__(16) ushort aHi[16 * 264], aLo[16 * 264];
    __shared__ __align__(16) ushort bHi[16 * 264], bLo[16 * 264];
    int t = threadIdx.x;
    int r0 = blockIdx.x * 16;
    #pragma unroll
    for (int ii = 0; ii < 2; ++ii) {
        int f4 = ii * 512 + t;
        int row = f4 >> 6, c = (f4 & 63) * 4;
        float4 xv = *(const float4*)(X + (r0 + row) * 256 + c);
        ushort h[4], l[4];
        split_bf16(xv.x, h[0], l[0]); split_bf16(xv.y, h[1], l[1]);
        split_bf16(xv.z, h[2], l[2]); split_bf16(xv.w, h[3], l[3]);
        uint2 ph = { (uint)h[0] | ((uint)h[1] << 16), (uint)h[2] | ((uint)h[3] << 16) };
        uint2 pl = { (uint)l[0] | ((uint)l[1] << 16), (uint)l[2] | ((uint)l[3] << 16) };
        *(uint2*)(aHi + row * 264 + c) = ph;
        *(uint2*)(aLo + row * 264 + c) = pl;
    }
    __syncthreads();
    int lane = t & 63, w = t >> 6;
    int lr = lane & 15, quad = lane >> 4;
    int aoff = lr * 264 + quad * 8;
    // ---- stage 1: mlp1 + gelu -> bHi/bLo
    {
        const uint4* H4 = (const uint4*)(Whi + 0 * 65536);
        const uint4* L4 = (const uint4*)(Wlo + 0 * 65536);
        f32x4 acc[2] = {};
        #pragma unroll
        for (int ks = 0; ks < 8; ++ks) {
            short8 a_h = lds_frag(aHi + aoff + ks * 32);
            short8 a_l = lds_frag(aLo + aoff + ks * 32);
            #pragma unroll
            for (int ti = 0; ti < 2; ++ti) {
                int off = ((w * 2 + ti) * 8 + ks) * 64 + lane;
                V8 bh, bl; bh.u = H4[off]; bl.u = L4[off];
                acc[ti] = __builtin_amdgcn_mfma_f32_16x16x32_bf16(a_h, bh.s, acc[ti], 0, 0, 0);
                acc[ti] = __builtin_amdgcn_mfma_f32_16x16x32_bf16(a_l, bh.s, acc[ti], 0, 0, 0);
                acc[ti] = __builtin_amdgcn_mfma_f32_16x16x32_bf16(a_h, bl.s, acc[ti], 0, 0, 0);
            }
        }
        #pragma unroll
        for (int ti = 0; ti < 2; ++ti) {
            int n0 = (w * 2 + ti) * 16 + lr;
            float bb = b1[n0];
            #pragma unroll
            for (int r = 0; r < 4; ++r) {
                float o = gelu_f(acc[ti][r] + bb);
                ushort hh, ll; split_bf16(o, hh, ll);
                int ad = (quad * 4 + r) * 264 + n0;
                bHi[ad] = hh; bLo[ad] = ll;
            }
        }
    }
    __syncthreads();
    // ---- stage 2: mlp2 -> aHi/aLo
    {
        const uint4* H4 = (const uint4*)(Whi + 1 * 65536);
        const uint4* L4 = (const uint4*)(Wlo + 1 * 65536);
        f32x4 acc[2] = {};
        #pragma unroll
        for (int ks = 0; ks < 8; ++ks) {
            short8 a_h = lds_frag(bHi + aoff + ks * 32);
            short8 a_l = lds_frag(bLo + aoff + ks * 32);
            #pragma unroll
            for (int ti = 0; ti < 2; ++ti) {
                int off = ((w * 2 + ti) * 8 + ks) * 64 + lane;
                V8 bh, bl; bh.u = H4[off]; bl.u = L4[off];
                acc[ti] = __builtin_amdgcn_mfma_f32_16x16x32_bf16(a_h, bh.s, acc[ti], 0, 0, 0);
                acc[ti] = __builtin_amdgcn_mfma_f32_16x16x32_bf16(a_l, bh.s, acc[ti], 0, 0, 0);
                acc[ti] = __builtin_amdgcn_mfma_f32_16x16x32_bf16(a_h, bl.s, acc[ti], 0, 0, 0);
            }
        }
        __syncthreads();
        #pragma unroll
        for (int ti = 0; ti < 2; ++ti) {
            int n0 = (w * 2 + ti) * 16 + lr;
            float bb = b2[n0];
            #pragma unroll
            for (int r = 0; r < 4; ++r) {
                float o = acc[ti][r] + bb;
                ushort hh, ll; split_bf16(o, hh, ll);
                int ad = (quad * 4 + r) * 264 + n0;
                aHi[ad] = hh; aLo[ad] = ll;
            }
        }
    }
    __syncthreads();
    // ---- stage 3: q/k/v -> global bf16
    {
        const uint4* Hq = (const uint4*)(Whi + 2 * 65536);
        const uint4* Lq = (const uint4*)(Wlo + 2 * 65536);
        const uint4* Hk = (const uint4*)(Whi + 3 * 65536);
        const uint4* Lk = (const uint4*)(Wlo + 3 * 65536);
        const uint4* Hv = (const uint4*)(Whi + 4 * 65536);
        const uint4* Lv = (const uint4*)(Wlo + 4 * 65536);
        f32x4 aq[2] = {}, ak[2] = {}, av[2] = {};
        #pragma unroll 2
        for (int ks = 0; ks < 8; ++ks) {
            short8 a_h = lds_frag(aHi + aoff + ks * 32);
            short8 a_l = lds_frag(aLo + aoff + ks * 32);
            #pragma unroll
            for (int ti = 0; ti < 2; ++ti) {
                int off = ((w * 2 + ti) * 8 + ks) * 64 + lane;
                V8 qh, ql, kh, kl, vh, vl;
                qh.u = Hq[off]; ql.u = Lq[off];
                kh.u = Hk[off]; kl.u = Lk[off];
                vh.u = Hv[off]; vl.u = Lv[off];
                aq[ti] = __builtin_amdgcn_mfma_f32_16x16x32_bf16(a_h, qh.s, aq[ti], 0, 0, 0);
                aq[ti] = __builtin_amdgcn_mfma_f32_16x16x32_bf16(a_l, qh.s, aq[ti], 0, 0, 0);
                aq[ti] = __builtin_amdgcn_mfma_f32_16x16x32_bf16(a_h, ql.s, aq[ti], 0, 0, 0);
                ak[ti] = __builtin_amdgcn_mfma_f32_16x16x32_bf16(a_h, kh.s, ak[ti], 0, 0, 0);
                ak[ti] = __builtin_amdgcn_mfma_f32_16x16x32_bf16(a_l, kh.s, ak[ti], 0, 0, 0);
                ak[ti] = __builtin_amdgcn_mfma_f32_16x16x32_bf16(a_h, kl.s, ak[ti], 0, 0, 0);
                av[ti] = __builtin_amdgcn_mfma_f32_16x16x32_bf16(a_h, vh.s, av[ti], 0, 0, 0);
                av[ti] = __builtin_amdgcn_mfma_f32_16x16x32_bf16(a_l, vh.s, av[ti], 0, 0, 0);
                av[ti] = __builtin_amdgcn_mfma_f32_16x16x32_bf16(a_h, vl.s, av[ti], 0, 0, 0);
            }
        }
        #pragma unroll
        for (int ti = 0; ti < 2; ++ti) {
            int n0 = (w * 2 + ti) * 16 + lr;
            float bq = Bq[n0], bk = Bk[n0], bv = Bv[n0];
            #pragma unroll
            for (int r = 0; r < 4; ++r) {
                int go = (r0 + quad * 4 + r) * 256 + n0;
                Q[go] = bf16bits(aq[ti][r] + bq);
                K[go] = bf16bits(ak[ti][r] + bk);
                V[go] = bf16bits(av[ti][r] + bv);
            }
        }
    }
}

// ---------------------------------------------------------------------------
// MFMA attention on bf16 Q/K/V: grid 512 = (b, h, rowhalf); 256 thr = 4 waves;
// wave w -> row tile rt = rh*4 + w. A/B frags are single uint4 loads.
// ---------------------------------------------------------------------------
__global__ __launch_bounds__(256) void k_attn_mfma(
    const ushort* __restrict__ Q, const ushort* __restrict__ K,
    const ushort* __restrict__ V, const ushort* __restrict__ maskb,
    float* __restrict__ AO) {
    int bx = blockIdx.x;
    int b = bx >> 4, h = (bx >> 1) & 7, rh = bx & 1;
    int t = threadIdx.x;
    int lane = t & 63, w = t >> 6;
    __shared__ __align__(16) ushort vT[32 * 136];
    __shared__ __align__(16) ushort ps[64 * 136];
    // stage V transposed from bf16 global (uint4 = 8 d-values per key)
    #pragma unroll
    for (int it = 0; it < 2; ++it) {
        int idx = it * 256 + t;               // 0..511
        int key = idx >> 2, dq8 = (idx & 3) * 8;
        V8 vv; vv.u = *(const uint4*)(V + (b * 128 + key) * 256 + h * 32 + dq8);
        #pragma unroll
        for (int m = 0; m < 8; ++m)
            vT[(dq8 + m) * 136 + key] = (ushort)vv.s[m];
    }
    __syncthreads();
    int lr = lane & 15, quad = lane >> 4;
    int rt = rh * 4 + w;
    // QK^T
    V8 af;
    af.u = *(const uint4*)(Q + (b * 128 + rt * 16 + lr) * 256 + h * 32 + quad * 8);
    f32x4 s[8];
    #pragma unroll
    for (int ct = 0; ct < 8; ++ct) {
        V8 bf_;
        bf_.u = *(const uint4*)(K + (b * 128 + ct * 16 + lr) * 256 + h * 32 + quad * 8);
        f32x4 z = {0.f, 0.f, 0.f, 0.f};
        s[ct] = __builtin_amdgcn_mfma_f32_16x16x32_bf16(af.s, bf_.s, z, 0, 0, 0);
    }
    const float scale = 0.17677669529663687f;  // 32^-0.5
    const ushort* mrow = maskb + h * 16384;
    #pragma unroll
    for (int r = 0; r < 4; ++r) {
        int lrow = w * 16 + quad * 4 + r;
        int grow = rt * 16 + quad * 4 + r;
        float sv[8];
        float mx = -3.0e38f;
        #pragma unroll
        for (int ct = 0; ct < 8; ++ct) {
            float bias = bits_to_f(mrow[grow * 128 + ct * 16 + lr]);
            sv[ct] = s[ct][r] * scale + bias;
            mx = fmaxf(mx, sv[ct]);
        }
        mx = fmaxf(mx, __shfl_xor(mx, 1));
        mx = fmaxf(mx, __shfl_xor(mx, 2));
        mx = fmaxf(mx, __shfl_xor(mx, 4));
        mx = fmaxf(mx, __shfl_xor(mx, 8));
        float sum = 0.f;
        #pragma unroll
        for (int ct = 0; ct < 8; ++ct) {
            sv[ct] = __expf(sv[ct] - mx);
            sum += sv[ct];
        }
        sum += __shfl_xor(sum, 1);
        sum += __shfl_xor(sum, 2);
        sum += __shfl_xor(sum, 4);
        sum += __shfl_xor(sum, 8);
        float iv = 1.f / sum;
        #pragma unroll
        for (int ct = 0; ct < 8; ++ct)
            ps[lrow * 136 + ct * 16 + lr] = bf16bits(sv[ct] * iv);
    }
    // PV (rows wave-private)
    f32x4 o0 = {}, o1 = {};
    #pragma unroll
    for (int kk = 0; kk < 4; ++kk) {
        short8 pa = lds_frag(ps + (w * 16 + lr) * 136 + kk * 32 + quad * 8);
        short8 v0 = lds_frag(vT + lr * 136 + kk * 32 + quad * 8);
        short8 v1 = lds_frag(vT + (16 + lr) * 136 + kk * 32 + quad * 8);
        o0 = __builtin_amdgcn_mfma_f32_16x16x32_bf16(pa, v0, o0, 0, 0, 0);
        o1 = __builtin_amdgcn_mfma_f32_16x16x32_bf16(pa, v1, o1, 0, 0, 0);
    }
    #pragma unroll
    for (int r = 0; r < 4; ++r) {
        int grow = rt * 16 + quad * 4 + r;
        float* op = AO + b * 32768 + grow * 256 + h * 32;
        op[lr] = o0[r];
        op[16 + lr] = o1[r];
    }
}

// ---------------------------------------------------------------------------
// Out-proj MFMA GEMM: Y[4096,256] = X @ W + b. grid (256 rowtiles, 4 colquads),
// 256 thr = 4 waves; wave w -> coltile tg = cq*4 + w.
// ---------------------------------------------------------------------------
__global__ __launch_bounds__(256) void k_gemm16(
    const float* __restrict__ X, const ushort* __restrict__ Whi,
    const ushort* __restrict__ Wlo, const float* __restrict__ bias,
    float* __restrict__ Y) {
    __shared__ __align__(16) ushort xhi[16 * 264], xlo[16 * 264];
    int t = threadIdx.x;
    int r0 = blockIdx.x * 16;
    #pragma unroll
    for (int ii = 0; ii < 4; ++ii) {
        int f4 = ii * 256 + t;
        int row = f4 >> 6, c = (f4 & 63) * 4;
        float4 xv = *(const float4*)(X + (r0 + row) * 256 + c);
        ushort h[4], l[4];
        split_bf16(xv.x, h[0], l[0]); split_bf16(xv.y, h[1], l[1]);
        split_bf16(xv.z, h[2], l[2]); split_bf16(xv.w, h[3], l[3]);
        uint2 ph = { (uint)h[0] | ((uint)h[1] << 16), (uint)h[2] | ((uint)h[3] << 16) };
        uint2 pl = { (uint)l[0] | ((uint)l[1] << 16), (uint)l[2] | ((uint)l[3] << 16) };
        *(uint2*)(xhi + row * 264 + c) = ph;
        *(uint2*)(xlo + row * 264 + c) = pl;
    }
    __syncthreads();
    int l = t & 63, w = t >> 6;
    int lr = l & 15, quad = l >> 4;
    int tg = blockIdx.y * 4 + w;
    const ushort* ah = xhi + lr * 264 + quad * 8;
    const ushort* al = xlo + lr * 264 + quad * 8;
    const uint4* H4 = (const uint4*)Whi;
    const uint4* L4 = (const uint4*)Wlo;
    f32x4 acc = {};
    #pragma unroll
    for (int ks = 0; ks < 8; ++ks) {
        short8 a_h = lds_frag(ah + ks * 32);
        short8 a_l = lds_frag(al + ks * 32);
        int off = (tg * 8 + ks) * 64 + l;
        V8 bh, bl; bh.u = H4[off]; bl.u = L4[off];
        acc = __builtin_amdgcn_mfma_f32_16x16x32_bf16(a_h, bh.s, acc, 0, 0, 0);
        acc = __builtin_amdgcn_mfma_f32_16x16x32_bf16(a_l, bh.s, acc, 0, 0, 0);
        acc = __builtin_amdgcn_mfma_f32_16x16x32_bf16(a_h, bl.s, acc, 0, 0, 0);
    }
    int n0 = tg * 16 + lr;
    float bs = bias[n0];
    #pragma unroll
    for (int r = 0; r < 4; ++r)
        Y[(r0 + quad * 4 + r) * 256 + n0] = acc[r] + bs;
}

// ---------------------------------------------------------------------------
extern "C" void kernel_launch(void* const* d_in, const int* in_sizes, int n_in,
                              void* d_out, int out_size, void* d_ws, size_t ws_size,
                              hipStream_t stream) {
    const float* x        = (const float*)d_in[0];
    const float* gumbel_u = (const float*)d_in[1];
    const float* memory_w = (const float*)d_in[2];
    const float* fc_out_w = (const float*)d_in[3];
    const float* fc_out_b = (const float*)d_in[4];
    const float* fc_cat_w = (const float*)d_in[5];
    const float* fc_cat_b = (const float*)d_in[6];
    const float* wq       = (const float*)d_in[7];
    const float* bq       = (const float*)d_in[8];
    const float* wk       = (const float*)d_in[9];
    const float* bk       = (const float*)d_in[10];
    const float* wv_      = (const float*)d_in[11];
    const float* bv_      = (const float*)d_in[12];
    const float* out_w    = (const float*)d_in[13];
    const float* out_b    = (const float*)d_in[14];
    const float* mlp_w1   = (const float*)d_in[15];
    const float* mlp_b1   = (const float*)d_in[16];
    const float* mlp_w2   = (const float*)d_in[17];
    const float* mlp_b2   = (const float*)d_in[18];

    // Workspace layout (units: floats). NOTE: 1,048,576 ushorts = 524,288
    // floats — the R8 failure was sizing these as 262,144 (qb/kb/vb/ao
    // overlapped; attention read clobbered V and wrote ao on top of vb).
    float* ws    = (float*)d_ws;
    float* A     = ws;                        //        0 .. 262144
    float* Bm    = ws + 262144;               //   262144 .. 524288
    ushort* mask = (ushort*)(ws + 524288);    //   524288 .. 589824  (131072 us)
    ushort* qb   = (ushort*)(ws + 589824);    //   589824 .. 1114112 (1048576 us)
    ushort* kb   = (ushort*)(ws + 1114112);   //  1114112 .. 1638400
    ushort* vb   = (ushort*)(ws + 1638400);   //  1638400 .. 2162688
    float* ao    = ws + 2162688;              //  2162688 .. 3211264 (1048576 f)
    ushort* wf_hi = (ushort*)(ws + 3211264);  //  3211264 .. 3473408 (524288 us)
    ushort* wf_lo = wf_hi + 8 * 65536;        //  3473408 .. 3735552
    float* out   = (float*)d_out;

    // weight order: 0=mlp_w1 1=mlp_w2 2=wq 3=wk 4=wv 5=out_w 6,7=fc_out halves
    k_wprep<<<dim3(128), dim3(256), 0, stream>>>(
        mlp_w1, mlp_w2, wq, wk, wv_, out_w, fc_out_w, fc_out_w + 65536,
        wf_hi, wf_lo);
    k_featproj<<<dim3(64, 8), dim3(256), 0, stream>>>(memory_w, wf_hi, wf_lo, A, Bm);
    k_fused3<<<dim3(256), dim3(512), 0, stream>>>(x, wf_hi, wf_lo, mlp_b1, mlp_b2,
                                                  bq, bk, bv_, qb, kb, vb);
    k_conn<<<dim3(512), dim3(256), 0, stream>>>(A, Bm, fc_out_b, fc_cat_w, fc_cat_b,
                                                gumbel_u, mask);
    k_attn_mfma<<<dim3(512), dim3(256), 0, stream>>>(qb, kb, vb, mask, ao);
    k_gemm16<<<dim3(256, 4), dim3(256), 0, stream>>>(ao, wf_hi + 5 * 65536,
                                                     wf_lo + 5 * 65536, out_b, out);
}

// Round 11
// 144.641 us; speedup vs baseline: 3.3632x; 1.1008x over previous
//
#include <hip/hip_runtime.h>
#include <hip/hip_bf16.h>
#include <math.h>

// Problem constants: H=8, d_model=256, N=128, d_k=32, B=32, rows=4096

typedef short short8 __attribute__((ext_vector_type(8)));
typedef float f32x4 __attribute__((ext_vector_type(4)));

union V8 { uint4 u; short8 s; };

__device__ __forceinline__ float gelu_f(float x) {
    float inner = 0.7978845608028654f * (x + 0.044715f * x * x * x);
    return 0.5f * x * (1.0f + tanhf(inner));
}
__device__ __forceinline__ void split_bf16(float x, ushort& h, ushort& l) {
    __hip_bfloat16 bh = __float2bfloat16(x);          // RN
    float hf = __bfloat162float(bh);
    __hip_bfloat16 bl = __float2bfloat16(x - hf);
    h = __builtin_bit_cast(ushort, bh);
    l = __builtin_bit_cast(ushort, bl);
}
__device__ __forceinline__ ushort bf16bits(float x) {
    return __builtin_bit_cast(ushort, __float2bfloat16(x));
}
__device__ __forceinline__ float bits_to_f(ushort v) {
    return __builtin_bit_cast(float, ((uint)v) << 16);
}
__device__ __forceinline__ short8 lds_frag(const ushort* p) {
    V8 v; v.u = *(const uint4*)p; return v.s;
}

// Frag layout for all prepped weights: elem (k,n) of mat m lives at
//   m*65536 + ((tg*8+ks)*64 + lane)*8 + j
// with tg=n>>4, lr=n&15, ks=k>>5, quad=(k>>3)&3, j=k&7, lane=quad*16+lr.
// Mats: 0=mlp_w1 1=mlp_w2 2=wq 3=wk 4=wv 5=out_w 6=fc_out_w[0:256] 7=[256:512]

// ---------------------------------------------------------------------------
// Dispatch 1: wprep only (64 blocks x 512 thr, two 256-thr jobs per block).
// MUST be its own dispatch: featproj/fused3 read its output (R10's race).
// ---------------------------------------------------------------------------
__global__ __launch_bounds__(512) void k_wprep(
    const float* __restrict__ mlp_w1, const float* __restrict__ mlp_w2,
    const float* __restrict__ wq, const float* __restrict__ wk,
    const float* __restrict__ wv, const float* __restrict__ out_w,
    const float* __restrict__ fc_out_w,
    ushort* __restrict__ hi, ushort* __restrict__ lo) {
    __shared__ __align__(16) float xs2[2][32 * 132];
    int bx = blockIdx.x, t = threadIdx.x;
    int half = t >> 8, tl = t & 255;
    int job = bx * 2 + half;                      // 0..127
    int m = job >> 4, ks = (job >> 1) & 7, nh = job & 1;
    const float* W = m == 0 ? mlp_w1 : m == 1 ? mlp_w2 : m == 2 ? wq :
                     m == 3 ? wk : m == 4 ? wv : m == 5 ? out_w :
                     m == 6 ? fc_out_w : fc_out_w + 65536;
    ushort* Hm = hi + m * 65536;
    ushort* Lm = lo + m * 65536;
    float* xs = xs2[half];
    #pragma unroll
    for (int p = 0; p < 4; ++p) {
        int idx = p * 256 + tl;
        int row = idx >> 5, c4 = (idx & 31) * 4;
        *(float4*)(xs + row * 132 + c4) =
            *(const float4*)(W + (ks * 32 + row) * 256 + nh * 128 + c4);
    }
    __syncthreads();
    int lane = tl & 63, lr = lane & 15, quad = lane >> 4;
    #pragma unroll
    for (int it = 0; it < 2; ++it) {
        int tgl = (tl >> 6) + 4 * it;
        int tg = nh * 8 + tgl;
        int nl = tgl * 16 + lr;
        ushort hb[8], lb[8];
        #pragma unroll
        for (int j = 0; j < 8; ++j)
            split_bf16(xs[(quad * 8 + j) * 132 + nl], hb[j], lb[j]);
        uint4 ph = { (uint)hb[0] | ((uint)hb[1] << 16), (uint)hb[2] | ((uint)hb[3] << 16),
                     (uint)hb[4] | ((uint)hb[5] << 16), (uint)hb[6] | ((uint)hb[7] << 16) };
        uint4 pl = { (uint)lb[0] | ((uint)lb[1] << 16), (uint)lb[2] | ((uint)lb[3] << 16),
                     (uint)lb[4] | ((uint)lb[5] << 16), (uint)lb[6] | ((uint)lb[7] << 16) };
        int idx = ((tg * 8 + ks) * 64 + lane) * 8;
        *(uint4*)(Hm + idx) = ph;
        *(uint4*)(Lm + idx) = pl;
    }
}

// ---------------------------------------------------------------------------
// Dispatch 2: blocks 0..63 = featproj (stage once, 8 waves cover all jobs);
//             blocks 64..319 = fused3 (mlp1->mlp2->qkv, bf16 out).
// Both only READ wf_hi/wf_lo (D1 output); writes are disjoint. 512 threads.
// ---------------------------------------------------------------------------
__global__ __launch_bounds__(512) void k_p2(
    const float* __restrict__ memory_w, const float* __restrict__ X,
    const ushort* __restrict__ Whi, const ushort* __restrict__ Wlo,
    const float* __restrict__ b1, const float* __restrict__ b2,
    const float* __restrict__ Bq, const float* __restrict__ Bk,
    const float* __restrict__ Bv,
    float* __restrict__ A, float* __restrict__ Bm,
    ushort* __restrict__ Q, ushort* __restrict__ K, ushort* __restrict__ V) {
    __shared__ __align__(16) union {
        struct { ushort xhi[16 * 264], xlo[16 * 264]; } f;   // featproj 16.9 KB
        struct {
            ushort aHi[16 * 264], aLo[16 * 264];
            ushort bHi[16 * 264], bLo[16 * 264];
        } g;                                                  // fused3 33.8 KB
    } sm;
    int bx = blockIdx.x, t = threadIdx.x;
    if (bx < 64) {
        // ---- featproj: rt = bx; one staged tile serves all 8 (msel,cq)
        int rt = bx;
        #pragma unroll
        for (int ii = 0; ii < 2; ++ii) {
            int f4 = ii * 512 + t;
            int rr = f4 >> 6, c = (f4 & 63) * 4;
            int r = rt * 16 + rr;
            int h = r >> 7, n = r & 127;
            float4 xv = *(const float4*)(memory_w + n * 2048 + h * 256 + c);
            ushort hh[4], ll[4];
            split_bf16(xv.x, hh[0], ll[0]); split_bf16(xv.y, hh[1], ll[1]);
            split_bf16(xv.z, hh[2], ll[2]); split_bf16(xv.w, hh[3], ll[3]);
            uint2 ph = { (uint)hh[0] | ((uint)hh[1] << 16), (uint)hh[2] | ((uint)hh[3] << 16) };
            uint2 pl = { (uint)ll[0] | ((uint)ll[1] << 16), (uint)ll[2] | ((uint)ll[3] << 16) };
            *(uint2*)(sm.f.xhi + rr * 264 + c) = ph;
            *(uint2*)(sm.f.xlo + rr * 264 + c) = pl;
        }
        __syncthreads();
        int lane = t & 63, w = t >> 6;
        int lr = lane & 15, quad = lane >> 4;
        int msel = w & 1, cq = w >> 1;
        const uint4* H4 = (const uint4*)(Whi + (6 + msel) * 65536);
        const uint4* L4 = (const uint4*)(Wlo + (6 + msel) * 65536);
        const ushort* ah = sm.f.xhi + lr * 264 + quad * 8;
        const ushort* al = sm.f.xlo + lr * 264 + quad * 8;
        float* O = msel ? Bm : A;
        #pragma unroll
        for (int i = 0; i < 4; ++i) {
            int tg = cq * 4 + i;
            f32x4 acc = {};
            #pragma unroll
            for (int ks = 0; ks < 8; ++ks) {
                short8 a_h = lds_frag(ah + ks * 32);
                short8 a_l = lds_frag(al + ks * 32);
                int off = (tg * 8 + ks) * 64 + lane;
                V8 bh, bl; bh.u = H4[off]; bl.u = L4[off];
                acc = __builtin_amdgcn_mfma_f32_16x16x32_bf16(a_h, bh.s, acc, 0, 0, 0);
                acc = __builtin_amdgcn_mfma_f32_16x16x32_bf16(a_l, bh.s, acc, 0, 0, 0);
                acc = __builtin_amdgcn_mfma_f32_16x16x32_bf16(a_h, bl.s, acc, 0, 0, 0);
            }
            int n0 = tg * 16 + lr;
            #pragma unroll
            for (int r = 0; r < 4; ++r)
                O[(rt * 16 + quad * 4 + r) * 256 + n0] = acc[r];
        }
        return;
    }
    // ================= fused3 (identical math to R9) =================
    int r0 = (bx - 64) * 16;
    #pragma unroll
    for (int ii = 0; ii < 2; ++ii) {
        int f4 = ii * 512 + t;
        int row = f4 >> 6, c = (f4 & 63) * 4;
        float4 xv = *(const float4*)(X + (r0 + row) * 256 + c);
        ushort h[4], l[4];
        split_bf16(xv.x, h[0], l[0]); split_bf16(xv.y, h[1], l[1]);
        split_bf16(xv.z, h[2], l[2]); split_bf16(xv.w, h[3], l[3]);
        uint2 ph = { (uint)h[0] | ((uint)h[1] << 16), (uint)h[2] | ((uint)h[3] << 16) };
        uint2 pl = { (uint)l[0] | ((uint)l[1] << 16), (uint)l[2] | ((uint)l[3] << 16) };
        *(uint2*)(sm.g.aHi + row * 264 + c) = ph;
        *(uint2*)(sm.g.aLo + row * 264 + c) = pl;
    }
    __syncthreads();
    int lane = t & 63, w = t >> 6;
    int lr = lane & 15, quad = lane >> 4;
    int aoff = lr * 264 + quad * 8;
    // stage 1: mlp1 + gelu
    {
        const uint4* H4 = (const uint4*)(Whi + 0 * 65536);
        const uint4* L4 = (const uint4*)(Wlo + 0 * 65536);
        f32x4 acc[2] = {};
        #pragma unroll
        for (int ks = 0; ks < 8; ++ks) {
            short8 a_h = lds_frag(sm.g.aHi + aoff + ks * 32);
            short8 a_l = lds_frag(sm.g.aLo + aoff + ks * 32);
            #pragma unroll
            for (int ti = 0; ti < 2; ++ti) {
                int off = ((w * 2 + ti) * 8 + ks) * 64 + lane;
                V8 bh, bl; bh.u = H4[off]; bl.u = L4[off];
                acc[ti] = __builtin_amdgcn_mfma_f32_16x16x32_bf16(a_h, bh.s, acc[ti], 0, 0, 0);
                acc[ti] = __builtin_amdgcn_mfma_f32_16x16x32_bf16(a_l, bh.s, acc[ti], 0, 0, 0);
                acc[ti] = __builtin_amdgcn_mfma_f32_16x16x32_bf16(a_h, bl.s, acc[ti], 0, 0, 0);
            }
        }
        #pragma unroll
        for (int ti = 0; ti < 2; ++ti) {
            int n0 = (w * 2 + ti) * 16 + lr;
            float bb = b1[n0];
            #pragma unroll
            for (int r = 0; r < 4; ++r) {
                float o = gelu_f(acc[ti][r] + bb);
                ushort hh, ll; split_bf16(o, hh, ll);
                int ad = (quad * 4 + r) * 264 + n0;
                sm.g.bHi[ad] = hh; sm.g.bLo[ad] = ll;
            }
        }
    }
    __syncthreads();
    // stage 2: mlp2
    {
        const uint4* H4 = (const uint4*)(Whi + 1 * 65536);
        const uint4* L4 = (const uint4*)(Wlo + 1 * 65536);
        f32x4 acc[2] = {};
        #pragma unroll
        for (int ks = 0; ks < 8; ++ks) {
            short8 a_h = lds_frag(sm.g.bHi + aoff + ks * 32);
            short8 a_l = lds_frag(sm.g.bLo + aoff + ks * 32);
            #pragma unroll
            for (int ti = 0; ti < 2; ++ti) {
                int off = ((w * 2 + ti) * 8 + ks) * 64 + lane;
                V8 bh, bl; bh.u = H4[off]; bl.u = L4[off];
                acc[ti] = __builtin_amdgcn_mfma_f32_16x16x32_bf16(a_h, bh.s, acc[ti], 0, 0, 0);
                acc[ti] = __builtin_amdgcn_mfma_f32_16x16x32_bf16(a_l, bh.s, acc[ti], 0, 0, 0);
                acc[ti] = __builtin_amdgcn_mfma_f32_16x16x32_bf16(a_h, bl.s, acc[ti], 0, 0, 0);
            }
        }
        __syncthreads();
        #pragma unroll
        for (int ti = 0; ti < 2; ++ti) {
            int n0 = (w * 2 + ti) * 16 + lr;
            float bb = b2[n0];
            #pragma unroll
            for (int r = 0; r < 4; ++r) {
                float o = acc[ti][r] + bb;
                ushort hh, ll; split_bf16(o, hh, ll);
                int ad = (quad * 4 + r) * 264 + n0;
                sm.g.aHi[ad] = hh; sm.g.aLo[ad] = ll;
            }
        }
    }
    __syncthreads();
    // stage 3: qkv -> bf16 global
    {
        const uint4* Hq = (const uint4*)(Whi + 2 * 65536);
        const uint4* Lq = (const uint4*)(Wlo + 2 * 65536);
        const uint4* Hk = (const uint4*)(Whi + 3 * 65536);
        const uint4* Lk = (const uint4*)(Wlo + 3 * 65536);
        const uint4* Hv = (const uint4*)(Whi + 4 * 65536);
        const uint4* Lv = (const uint4*)(Wlo + 4 * 65536);
        f32x4 aq[2] = {}, ak[2] = {}, av[2] = {};
        #pragma unroll 2
        for (int ks = 0; ks < 8; ++ks) {
            short8 a_h = lds_frag(sm.g.aHi + aoff + ks * 32);
            short8 a_l = lds_frag(sm.g.aLo + aoff + ks * 32);
            #pragma unroll
            for (int ti = 0; ti < 2; ++ti) {
                int off = ((w * 2 + ti) * 8 + ks) * 64 + lane;
                V8 qh, ql, kh, kl, vh, vl;
                qh.u = Hq[off]; ql.u = Lq[off];
                kh.u = Hk[off]; kl.u = Lk[off];
                vh.u = Hv[off]; vl.u = Lv[off];
                aq[ti] = __builtin_amdgcn_mfma_f32_16x16x32_bf16(a_h, qh.s, aq[ti], 0, 0, 0);
                aq[ti] = __builtin_amdgcn_mfma_f32_16x16x32_bf16(a_l, qh.s, aq[ti], 0, 0, 0);
                aq[ti] = __builtin_amdgcn_mfma_f32_16x16x32_bf16(a_h, ql.s, aq[ti], 0, 0, 0);
                ak[ti] = __builtin_amdgcn_mfma_f32_16x16x32_bf16(a_h, kh.s, ak[ti], 0, 0, 0);
                ak[ti] = __builtin_amdgcn_mfma_f32_16x16x32_bf16(a_l, kh.s, ak[ti], 0, 0, 0);
                ak[ti] = __builtin_amdgcn_mfma_f32_16x16x32_bf16(a_h, kl.s, ak[ti], 0, 0, 0);
                av[ti] = __builtin_amdgcn_mfma_f32_16x16x32_bf16(a_h, vh.s, av[ti], 0, 0, 0);
                av[ti] = __builtin_amdgcn_mfma_f32_16x16x32_bf16(a_l, vh.s, av[ti], 0, 0, 0);
                av[ti] = __builtin_amdgcn_mfma_f32_16x16x32_bf16(a_h, vl.s, av[ti], 0, 0, 0);
            }
        }
        #pragma unroll
        for (int ti = 0; ti < 2; ++ti) {
            int n0 = (w * 2 + ti) * 16 + lr;
            float bq = Bq[n0], bk = Bk[n0], bv = Bv[n0];
            #pragma unroll
            for (int r = 0; r < 4; ++r) {
                int go = (r0 + quad * 4 + r) * 256 + n0;
                Q[go] = bf16bits(aq[ti][r] + bq);
                K[go] = bf16bits(ak[ti][r] + bk);
                V[go] = bf16bits(av[ti][r] + bv);
            }
        }
    }
}

// ---------------------------------------------------------------------------
// Dispatch 3: conn (32i x 16j tiles). 256 blocks x 512 thr.
// ---------------------------------------------------------------------------
__global__ __launch_bounds__(512) void k_conn(
    const float* __restrict__ A, const float* __restrict__ Bmat,
    const float* __restrict__ fc_out_b, const float* __restrict__ fc_cat_w,
    const float* __restrict__ fc_cat_b, const float* __restrict__ gumbel_u,
    ushort* __restrict__ maskb) {
    __shared__ __align__(16) float sA[16 * 260], sB[32 * 260];
    int bx = blockIdx.x, t = threadIdx.x;
    int h = bx >> 5;
    int rem = bx & 31;
    int it = rem >> 3, jt = rem & 7;    // it 0..3, jt 0..7
    int i0 = it * 32, j0 = jt * 16;
    int jl = t & 15, il = t >> 4;       // jl 0..15, il 0..31
    #pragma unroll
    for (int p = 0; p < 6; ++p) {
        int id2 = p * 512 + t;          // 0..3071
        if (id2 < 1024) {
            int rr = id2 >> 6, c = (id2 & 63) * 4;
            *(float4*)(sA + rr * 260 + c) =
                *(const float4*)(A + (h * 128 + j0 + rr) * 256 + c);
        } else {
            int id3 = id2 - 1024;
            int rr = id3 >> 6, c = (id3 & 63) * 4;
            float4 bv = *(const float4*)(Bmat + (h * 128 + i0 + rr) * 256 + c);
            float4 fb = *(const float4*)(fc_out_b + c);
            bv.x += fb.x; bv.y += fb.y; bv.z += fb.z; bv.w += fb.w;
            *(float4*)(sB + rr * 260 + c) = bv;
        }
    }
    __syncthreads();
    const float* Ar = sA + jl * 260;
    const float* Br = sB + il * 260;
    float l0 = fc_cat_b[0], l1 = fc_cat_b[1];
    #pragma unroll 4
    for (int d4 = 0; d4 < 64; ++d4) {
        int d = d4 * 4;
        float4 av = *(const float4*)(Ar + d);
        float4 bv = *(const float4*)(Br + d);
        float4 cwA = *(const float4*)(fc_cat_w + d * 2);
        float4 cwB = *(const float4*)(fc_cat_w + d * 2 + 4);
        float h0 = fmaxf(av.x + bv.x, 0.f);
        float h1 = fmaxf(av.y + bv.y, 0.f);
        float h2 = fmaxf(av.z + bv.z, 0.f);
        float h3 = fmaxf(av.w + bv.w, 0.f);
        l0 += h0 * cwA.x + h1 * cwA.z + h2 * cwB.x + h3 * cwB.z;
        l1 += h0 * cwA.y + h1 * cwA.w + h2 * cwB.y + h3 * cwB.w;
    }
    int i = i0 + il, j = j0 + jl;
    float2 uu = *(const float2*)(gumbel_u + ((h * 128 + i) * 128 + j) * 2);
    float g0 = -logf(-logf(uu.x + 1e-10f) + 1e-10f);
    float g1 = -logf(-logf(uu.y + 1e-10f) + 1e-10f);
    bool on = (l1 + g1) > (l0 + g0);
    maskb[(h * 128 + i) * 128 + j] = bf16bits(on ? 0.f : -1e9f);
}

// ---------------------------------------------------------------------------
// Dispatch 4: MFMA attention on bf16 Q/K/V. grid 512 = (b, h, rowhalf);
// 256 thr = 4 waves; wave w -> row tile rt = rh*4 + w.
// ---------------------------------------------------------------------------
__global__ __launch_bounds__(256) void k_attn_mfma(
    const ushort* __restrict__ Q, const ushort* __restrict__ K,
    const ushort* __restrict__ V, const ushort* __restrict__ maskb,
    float* __restrict__ AO) {
    int bx = blockIdx.x;
    int b = bx >> 4, h = (bx >> 1) & 7, rh = bx & 1;
    int t = threadIdx.x;
    int lane = t & 63, w = t >> 6;
    __shared__ __align__(16) ushort vT[32 * 136];
    __shared__ __align__(16) ushort ps[64 * 136];
    #pragma unroll
    for (int it = 0; it < 2; ++it) {
        int idx = it * 256 + t;
        int key = idx >> 2, dq8 = (idx & 3) * 8;
        V8 vv; vv.u = *(const uint4*)(V + (b * 128 + key) * 256 + h * 32 + dq8);
        #pragma unroll
        for (int m = 0; m < 8; ++m)
            vT[(dq8 + m) * 136 + key] = (ushort)vv.s[m];
    }
    __syncthreads();
    int lr = lane & 15, quad = lane >> 4;
    int rt = rh * 4 + w;
    V8 af;
    af.u = *(const uint4*)(Q + (b * 128 + rt * 16 + lr) * 256 + h * 32 + quad * 8);
    f32x4 s[8];
    #pragma unroll
    for (int ct = 0; ct < 8; ++ct) {
        V8 bf_;
        bf_.u = *(const uint4*)(K + (b * 128 + ct * 16 + lr) * 256 + h * 32 + quad * 8);
        f32x4 z = {0.f, 0.f, 0.f, 0.f};
        s[ct] = __builtin_amdgcn_mfma_f32_16x16x32_bf16(af.s, bf_.s, z, 0, 0, 0);
    }
    const float scale = 0.17677669529663687f;  // 32^-0.5
    const ushort* mrow = maskb + h * 16384;
    #pragma unroll
    for (int r = 0; r < 4; ++r) {
        int lrow = w * 16 + quad * 4 + r;
        int grow = rt * 16 + quad * 4 + r;
        float sv[8];
        float mx = -3.0e38f;
        #pragma unroll
        for (int ct = 0; ct < 8; ++ct) {
            float bias = bits_to_f(mrow[grow * 128 + ct * 16 + lr]);
            sv[ct] = s[ct][r] * scale + bias;
            mx = fmaxf(mx, sv[ct]);
        }
        mx = fmaxf(mx, __shfl_xor(mx, 1));
        mx = fmaxf(mx, __shfl_xor(mx, 2));
        mx = fmaxf(mx, __shfl_xor(mx, 4));
        mx = fmaxf(mx, __shfl_xor(mx, 8));
        float sum = 0.f;
        #pragma unroll
        for (int ct = 0; ct < 8; ++ct) {
            sv[ct] = __expf(sv[ct] - mx);
            sum += sv[ct];
        }
        sum += __shfl_xor(sum, 1);
        sum += __shfl_xor(sum, 2);
        sum += __shfl_xor(sum, 4);
        sum += __shfl_xor(sum, 8);
        float iv = 1.f / sum;
        #pragma unroll
        for (int ct = 0; ct < 8; ++ct)
            ps[lrow * 136 + ct * 16 + lr] = bf16bits(sv[ct] * iv);
    }
    f32x4 o0 = {}, o1 = {};
    #pragma unroll
    for (int kk = 0; kk < 4; ++kk) {
        short8 pa = lds_frag(ps + (w * 16 + lr) * 136 + kk * 32 + quad * 8);
        short8 v0 = lds_frag(vT + lr * 136 + kk * 32 + quad * 8);
        short8 v1 = lds_frag(vT + (16 + lr) * 136 + kk * 32 + quad * 8);
        o0 = __builtin_amdgcn_mfma_f32_16x16x32_bf16(pa, v0, o0, 0, 0, 0);
        o1 = __builtin_amdgcn_mfma_f32_16x16x32_bf16(pa, v1, o1, 0, 0, 0);
    }
    #pragma unroll
    for (int r = 0; r < 4; ++r) {
        int grow = rt * 16 + quad * 4 + r;
        float* op = AO + b * 32768 + grow * 256 + h * 32;
        op[lr] = o0[r];
        op[16 + lr] = o1[r];
    }
}

// ---------------------------------------------------------------------------
// Dispatch 5: out-proj GEMM. grid (256 rowtiles, 4 colquads), 256 thr.
// ---------------------------------------------------------------------------
__global__ __launch_bounds__(256) void k_gemm16(
    const float* __restrict__ X, const ushort* __restrict__ Whi,
    const ushort* __restrict__ Wlo, const float* __restrict__ bias,
    float* __restrict__ Y) {
    __shared__ __align__(16) ushort xhi[16 * 264], xlo[16 * 264];
    int t = threadIdx.x;
    int r0 = blockIdx.x * 16;
    #pragma unroll
    for (int ii = 0; ii < 4; ++ii) {
        int f4 = ii * 256 + t;
        int row = f4 >> 6, c = (f4 & 63) * 4;
        float4 xv = *(const float4*)(X + (r0 + row) * 256 + c);
        ushort h[4], l[4];
        split_bf16(xv.x, h[0], l[0]); split_bf16(xv.y, h[1], l[1]);
        split_bf16(xv.z, h[2], l[2]); split_bf16(xv.w, h[3], l[3]);
        uint2 ph = { (uint)h[0] | ((uint)h[1] << 16), (uint)h[2] | ((uint)h[3] << 16) };
        uint2 pl = { (uint)l[0] | ((uint)l[1] << 16), (uint)l[2] | ((uint)l[3] << 16) };
        *(uint2*)(xhi + row * 264 + c) = ph;
        *(uint2*)(xlo + row * 264 + c) = pl;
    }
    __syncthreads();
    int l = t & 63, w = t >> 6;
    int lr = l & 15, quad = l >> 4;
    int tg = blockIdx.y * 4 + w;
    const ushort* ah = xhi + lr * 264 + quad * 8;
    const ushort* al = xlo + lr * 264 + quad * 8;
    const uint4* H4 = (const uint4*)Whi;
    const uint4* L4 = (const uint4*)Wlo;
    f32x4 acc = {};
    #pragma unroll
    for (int ks = 0; ks < 8; ++ks) {
        short8 a_h = lds_frag(ah + ks * 32);
        short8 a_l = lds_frag(al + ks * 32);
        int off = (tg * 8 + ks) * 64 + l;
        V8 bh, bl; bh.u = H4[off]; bl.u = L4[off];
        acc = __builtin_amdgcn_mfma_f32_16x16x32_bf16(a_h, bh.s, acc, 0, 0, 0);
        acc = __builtin_amdgcn_mfma_f32_16x16x32_bf16(a_l, bh.s, acc, 0, 0, 0);
        acc = __builtin_amdgcn_mfma_f32_16x16x32_bf16(a_h, bl.s, acc, 0, 0, 0);
    }
    int n0 = tg * 16 + lr;
    float bs = bias[n0];
    #pragma unroll
    for (int r = 0; r < 4; ++r)
        Y[(r0 + quad * 4 + r) * 256 + n0] = acc[r] + bs;
}

// ---------------------------------------------------------------------------
extern "C" void kernel_launch(void* const* d_in, const int* in_sizes, int n_in,
                              void* d_out, int out_size, void* d_ws, size_t ws_size,
                              hipStream_t stream) {
    const float* x        = (const float*)d_in[0];
    const float* gumbel_u = (const float*)d_in[1];
    const float* memory_w = (const float*)d_in[2];
    const float* fc_out_w = (const float*)d_in[3];
    const float* fc_out_b = (const float*)d_in[4];
    const float* fc_cat_w = (const float*)d_in[5];
    const float* fc_cat_b = (const float*)d_in[6];
    const float* wq       = (const float*)d_in[7];
    const float* bq       = (const float*)d_in[8];
    const float* wk       = (const float*)d_in[9];
    const float* bk       = (const float*)d_in[10];
    const float* wv_      = (const float*)d_in[11];
    const float* bv_      = (const float*)d_in[12];
    const float* out_w    = (const float*)d_in[13];
    const float* out_b    = (const float*)d_in[14];
    const float* mlp_w1   = (const float*)d_in[15];
    const float* mlp_b1   = (const float*)d_in[16];
    const float* mlp_w2   = (const float*)d_in[17];
    const float* mlp_b2   = (const float*)d_in[18];

    // Workspace (floats). 1,048,576 ushorts = 524,288 floats.
    float* ws    = (float*)d_ws;
    float* A     = ws;                        //        0 .. 262144
    float* Bm    = ws + 262144;               //   262144 .. 524288
    ushort* mask = (ushort*)(ws + 524288);    //   524288 .. 589824
    ushort* qb   = (ushort*)(ws + 589824);    //   589824 .. 1114112
    ushort* kb   = (ushort*)(ws + 1114112);   //  1114112 .. 1638400
    ushort* vb   = (ushort*)(ws + 1638400);   //  1638400 .. 2162688
    float* ao    = ws + 2162688;              //  2162688 .. 3211264
    ushort* wf_hi = (ushort*)(ws + 3211264);  //  3211264 .. 3473408
    ushort* wf_lo = wf_hi + 8 * 65536;        //  3473408 .. 3735552
    float* out   = (float*)d_out;

    // DAG: wprep -> {featproj, fused3} -> conn -> attn -> gemm16 (5 levels).
    k_wprep<<<dim3(64), dim3(512), 0, stream>>>(
        mlp_w1, mlp_w2, wq, wk, wv_, out_w, fc_out_w, wf_hi, wf_lo);
    k_p2<<<dim3(320), dim3(512), 0, stream>>>(
        memory_w, x, wf_hi, wf_lo, mlp_b1, mlp_b2, bq, bk, bv_,
        A, Bm, qb, kb, vb);
    k_conn<<<dim3(256), dim3(512), 0, stream>>>(
        A, Bm, fc_out_b, fc_cat_w, fc_cat_b, gumbel_u, mask);
    k_attn_mfma<<<dim3(512), dim3(256), 0, stream>>>(qb, kb, vb, mask, ao);
    k_gemm16<<<dim3(256, 4), dim3(256), 0, stream>>>(ao, wf_hi + 5 * 65536,
                                                     wf_lo + 5 * 65536, out_b, out);
}